// Round 3
// baseline (1276.255 us; speedup 1.0000x reference)
//
#include <hip/hip_runtime.h>
#include <math.h>

typedef unsigned short u16;
typedef unsigned int u32;
typedef float floatx4 __attribute__((ext_vector_type(4)));
typedef __bf16 bf16x8 __attribute__((ext_vector_type(8)));

#define T_TOK 3152      // B*L = 16*197
#define SEQ 197
#define NH 12
#define LISTN 6848      // 107 tiles * 64 (worst-case aligned expert segments)

__device__ __forceinline__ float bf2f(u16 u) { return __uint_as_float(((u32)u) << 16); }
__device__ __forceinline__ u16 f2bf(float f) {
    u32 u = __float_as_uint(f);
    u += 0x7FFFu + ((u >> 16) & 1u);   // RNE
    return (u16)(u >> 16);
}
__device__ __forceinline__ float wred_sum(float v) {
#pragma unroll
    for (int off = 32; off; off >>= 1) v += __shfl_xor(v, off);
    return v;
}
__device__ __forceinline__ float wred_max(float v) {
#pragma unroll
    for (int off = 32; off; off >>= 1) v = fmaxf(v, __shfl_xor(v, off));
    return v;
}

// ---------------- LN1: h = LN(x)*g+b, split to bf16 hi/lo planes ----------------
__global__ __launch_bounds__(256) void ln1_kernel(const float* __restrict__ x,
        const float* __restrict__ g, const float* __restrict__ b,
        u16* __restrict__ h_hi, u16* __restrict__ h_lo) {
    int t = blockIdx.x, tid = threadIdx.x;
    int w = tid >> 6, lane = tid & 63;
    float v[3];
#pragma unroll
    for (int i = 0; i < 3; i++) v[i] = x[(size_t)t * 768 + tid + i * 256];
    float s = v[0] + v[1] + v[2];
    float q = v[0] * v[0] + v[1] * v[1] + v[2] * v[2];
    s = wred_sum(s); q = wred_sum(q);
    __shared__ float red[8];
    if (lane == 0) { red[w] = s; red[4 + w] = q; }
    __syncthreads();
    float st = red[0] + red[1] + red[2] + red[3];
    float qt = red[4] + red[5] + red[6] + red[7];
    float mean = st * (1.f / 768.f);
    float var = qt * (1.f / 768.f) - mean * mean;
    float rs = rsqrtf(var + 1e-5f);
#pragma unroll
    for (int i = 0; i < 3; i++) {
        int d = tid + i * 256;
        float hv = (v[i] - mean) * rs * g[d] + b[d];
        u16 hi = f2bf(hv);
        h_hi[(size_t)t * 768 + d] = hi;
        h_lo[(size_t)t * 768 + d] = f2bf(hv - bf2f(hi));
    }
}

// ---------------- split-bf16 GEMM (f32-grade): C = (Ah+Al)@(Bh+Bl) + bias ----------------
// SMODE 0: qkv   C(f32)[M,N] = A@B + bias
// SMODE 1: proj  C(f32)[M,N] = A@B + bias + resid
template <int SMODE>
__global__ __launch_bounds__(256) void gemm_split(const u16* __restrict__ Ah,
        const u16* __restrict__ Al, const float* __restrict__ B,
        const float* __restrict__ bias, float* __restrict__ C,
        const float* __restrict__ resid, int M, int N, int K) {
    int m0 = blockIdx.x * 64, n0 = blockIdx.y * 64;
    __shared__ u16 Ash[64 * 40], Asl[64 * 40];   // [m][k], stride 40
    __shared__ u16 Bsh[64 * 40], Bsl[64 * 40];   // transposed [n][k], stride 40
    int tid = threadIdx.x;
    int w = tid >> 6, lane = tid & 63, l15 = lane & 15, quad = lane >> 4;
    int arow = tid >> 2, acol = (tid & 3) * 8;
    int brow = tid >> 3, bcol = (tid & 7) * 8;

    const u16* ahp = nullptr;
    const u16* alp = nullptr;
    if (m0 + arow < M) {
        ahp = Ah + (size_t)(m0 + arow) * K;
        alp = Al + (size_t)(m0 + arow) * K;
    }

    floatx4 acc[4];
#pragma unroll
    for (int s = 0; s < 4; s++) acc[s] = (floatx4){0.f, 0.f, 0.f, 0.f};

    for (int k0 = 0; k0 < K; k0 += 32) {
        uint4 avh = make_uint4(0, 0, 0, 0), avl = make_uint4(0, 0, 0, 0);
        if (ahp) { avh = *(const uint4*)(ahp + k0 + acol); avl = *(const uint4*)(alp + k0 + acol); }
        *(uint4*)&Ash[arow * 40 + acol] = avh;
        *(uint4*)&Asl[arow * 40 + acol] = avl;
        const float* bsrc = B + (size_t)(k0 + brow) * N + n0 + bcol;
        float4 bv0 = *(const float4*)(bsrc);
        float4 bv1 = *(const float4*)(bsrc + 4);
        float bf[8] = {bv0.x, bv0.y, bv0.z, bv0.w, bv1.x, bv1.y, bv1.z, bv1.w};
#pragma unroll
        for (int j = 0; j < 8; j++) {
            u16 hb = f2bf(bf[j]);
            Bsh[(bcol + j) * 40 + brow] = hb;
            Bsl[(bcol + j) * 40 + brow] = f2bf(bf[j] - bf2f(hb));
        }
        __syncthreads();
        bf16x8 afh = *(const bf16x8*)&Ash[(w * 16 + l15) * 40 + quad * 8];
        bf16x8 afl = *(const bf16x8*)&Asl[(w * 16 + l15) * 40 + quad * 8];
#pragma unroll
        for (int s = 0; s < 4; s++) {
            bf16x8 bfh = *(const bf16x8*)&Bsh[(s * 16 + l15) * 40 + quad * 8];
            bf16x8 bfl = *(const bf16x8*)&Bsl[(s * 16 + l15) * 40 + quad * 8];
            acc[s] = __builtin_amdgcn_mfma_f32_16x16x32_bf16(afl, bfh, acc[s], 0, 0, 0);
            acc[s] = __builtin_amdgcn_mfma_f32_16x16x32_bf16(afh, bfl, acc[s], 0, 0, 0);
            acc[s] = __builtin_amdgcn_mfma_f32_16x16x32_bf16(afh, bfh, acc[s], 0, 0, 0);
        }
        __syncthreads();
    }

#pragma unroll
    for (int s = 0; s < 4; s++) {
        int col = n0 + s * 16 + l15;
        float bb = bias[col];
#pragma unroll
        for (int r = 0; r < 4; r++) {
            int row = m0 + w * 16 + quad * 4 + r;
            if (row < M) {
                float v = acc[s][r] + bb;
                if (SMODE == 1) v += resid[(size_t)row * N + col];
                C[(size_t)row * N + col] = v;
            }
        }
    }
}

// ---------------- MoE bf16 GEMM ----------------
// MODE 2: moe1  C(bf16)[p,N] = gelu(gather(A)@B_e + bias_e)   (A gathered via list)
// MODE 3: moe2  C(f32) [p,N] = A@B_e + bias_e                 (gate applied later)
template <int MODE>
__global__ __launch_bounds__(256) void gemm_kernel(const u16* __restrict__ A,
        const float* __restrict__ B, const float* __restrict__ bias, void* __restrict__ Cv,
        const int* __restrict__ list, const int* __restrict__ asg, int M, int N, int K) {
    int m0 = blockIdx.x * 64, n0 = blockIdx.y * 64;
    int a8 = asg[8];
    if (m0 >= a8) return;
    int e = 0;
    while (m0 >= asg[e + 1]) ++e;    // uniform across block
    const float* Bp = B + (size_t)e * K * N;
    const float* bp = bias + (size_t)e * N;

    __shared__ u16 As[64 * 40];          // [m][k], stride 40
    __shared__ u16 Bs[64 * 40];          // transposed [n][k], stride 40
    int tid = threadIdx.x;
    int w = tid >> 6, lane = tid & 63, l15 = lane & 15, quad = lane >> 4;
    int arow = tid >> 2, acol = (tid & 3) * 8;
    int brow = tid >> 3, bcol = (tid & 7) * 8;

    const u16* arp = nullptr;
    if (MODE == 2) {
        int entry = list[m0 + arow];
        if (entry >= 0) arp = A + (size_t)(entry >> 1) * K;
    } else {
        arp = A + (size_t)(m0 + arow) * K;   // padding rows hold finite poison; store-guarded
    }

    floatx4 acc[4];
#pragma unroll
    for (int s = 0; s < 4; s++) acc[s] = (floatx4){0.f, 0.f, 0.f, 0.f};

    for (int k0 = 0; k0 < K; k0 += 32) {
        uint4 av = make_uint4(0, 0, 0, 0);
        if (arp) av = *(const uint4*)(arp + k0 + acol);
        *(uint4*)&As[arow * 40 + acol] = av;
        const float* bsrc = Bp + (size_t)(k0 + brow) * N + n0 + bcol;
        float4 bv0 = *(const float4*)(bsrc);
        float4 bv1 = *(const float4*)(bsrc + 4);
        float bf[8] = {bv0.x, bv0.y, bv0.z, bv0.w, bv1.x, bv1.y, bv1.z, bv1.w};
#pragma unroll
        for (int j = 0; j < 8; j++) Bs[(bcol + j) * 40 + brow] = f2bf(bf[j]);
        __syncthreads();
        bf16x8 af = *(const bf16x8*)&As[(w * 16 + l15) * 40 + quad * 8];
#pragma unroll
        for (int s = 0; s < 4; s++) {
            bf16x8 bfr = *(const bf16x8*)&Bs[(s * 16 + l15) * 40 + quad * 8];
            acc[s] = __builtin_amdgcn_mfma_f32_16x16x32_bf16(af, bfr, acc[s], 0, 0, 0);
        }
        __syncthreads();
    }

#pragma unroll
    for (int s = 0; s < 4; s++) {
        int col = n0 + s * 16 + l15;
        float bb = bp[col];
#pragma unroll
        for (int r = 0; r < 4; r++) {
            int row = m0 + w * 16 + quad * 4 + r;
            float v = acc[s][r] + bb;
            if (list[row] >= 0) {
                if (MODE == 2) {
                    float gv = 0.5f * v * (1.f + erff(v * 0.70710678118f));  // exact gelu
                    ((u16*)Cv)[(size_t)row * N + col] = f2bf(gv);
                } else {
                    ((float*)Cv)[(size_t)row * N + col] = v;
                }
            }
        }
    }
}

// ---------------- attention: f32 in, one wave per (b,h,q-row); o split hi/lo ----------------
__global__ __launch_bounds__(256) void attn_kernel(const float* __restrict__ qkv,
        u16* __restrict__ ohi, u16* __restrict__ olo) {
    int w = threadIdx.x >> 6, lane = threadIdx.x & 63;
    int by = blockIdx.y;
    int b = by / NH, h = by % NH;
    int lq = blockIdx.x * 4 + w;
    bool valid = lq < SEQ;
    int lqc = valid ? lq : SEQ - 1;
    __shared__ float q_s[4][64];
    __shared__ float p_s[4][200];
    q_s[w][lane] = qkv[((size_t)(b * SEQ + lqc)) * 2304 + h * 64 + lane];
    __syncthreads();
    float s[4];
    float mx = -1e30f;
#pragma unroll
    for (int i = 0; i < 4; i++) {
        int key = lane + i * 64;
        s[i] = -1e30f;
        if (key < SEQ) {
            const float4* kp = (const float4*)(qkv + ((size_t)(b * SEQ + key)) * 2304 + 768 + h * 64);
            float acc = 0.f;
#pragma unroll
            for (int jj = 0; jj < 16; jj++) {
                float4 kv = kp[jj];
                acc += q_s[w][jj * 4 + 0] * kv.x + q_s[w][jj * 4 + 1] * kv.y
                     + q_s[w][jj * 4 + 2] * kv.z + q_s[w][jj * 4 + 3] * kv.w;
            }
            s[i] = acc * 0.125f;   // HD^-0.5
            mx = fmaxf(mx, s[i]);
        }
    }
    mx = wred_max(mx);
    float lsum = 0.f;
#pragma unroll
    for (int i = 0; i < 4; i++) {
        int key = lane + i * 64;
        if (key < SEQ) {
            float p = expf(s[i] - mx);
            p_s[w][key] = p;
            lsum += p;
        }
    }
    lsum = wred_sum(lsum);
    float inv = 1.f / lsum;
    int d = lane;
    float acc = 0.f;
    for (int key = 0; key < SEQ; key++) {
        acc += p_s[w][key] * qkv[((size_t)(b * SEQ + key)) * 2304 + 1536 + h * 64 + d];
    }
    if (valid) {
        float val = acc * inv;
        u16 hi = f2bf(val);
        size_t o = ((size_t)(b * SEQ + lq)) * 768 + h * 64 + d;
        ohi[o] = hi;
        olo[o] = f2bf(val - bf2f(hi));
    }
}

// ---------------- LN2 + gate (top-2 of 8) ----------------
__global__ __launch_bounds__(256) void ln2_gate_kernel(const float* __restrict__ x1,
        const float* __restrict__ g, const float* __restrict__ b, const float* __restrict__ wg,
        u16* __restrict__ flat, int2* __restrict__ idx, float2* __restrict__ gate) {
    int t = blockIdx.x, tid = threadIdx.x;
    int w = tid >> 6, lane = tid & 63;
    float v[3];
#pragma unroll
    for (int i = 0; i < 3; i++) v[i] = x1[(size_t)t * 768 + tid + i * 256];
    float s = v[0] + v[1] + v[2];
    float q = v[0] * v[0] + v[1] * v[1] + v[2] * v[2];
    s = wred_sum(s); q = wred_sum(q);
    __shared__ float red[8];
    __shared__ float fs[768];
    __shared__ float lg[8];
    if (lane == 0) { red[w] = s; red[4 + w] = q; }
    __syncthreads();
    float st = red[0] + red[1] + red[2] + red[3];
    float qt = red[4] + red[5] + red[6] + red[7];
    float mean = st * (1.f / 768.f);
    float var = qt * (1.f / 768.f) - mean * mean;
    float rs = rsqrtf(var + 1e-5f);
#pragma unroll
    for (int i = 0; i < 3; i++) {
        int d = tid + i * 256;
        float f = (v[i] - mean) * rs * g[d] + b[d];
        flat[(size_t)t * 768 + d] = f2bf(f);
        fs[d] = f;
    }
    __syncthreads();
    int e0 = 2 * w, e1 = 2 * w + 1;
    float p0 = 0.f, p1 = 0.f;
    for (int d = lane; d < 768; d += 64) {
        float f = fs[d];
        p0 += f * wg[d * 8 + e0];
        p1 += f * wg[d * 8 + e1];
    }
    p0 = wred_sum(p0); p1 = wred_sum(p1);
    if (lane == 0) { lg[e0] = p0; lg[e1] = p1; }
    __syncthreads();
    if (tid == 0) {
        float b0 = -1e30f, b1 = -1e30f;
        int i0 = 0, i1 = 0;
        for (int e = 0; e < 8; e++) {     // strict > keeps first occurrence (jax tie-break)
            float le = lg[e];
            if (le > b0) { b1 = b0; i1 = i0; b0 = le; i0 = e; }
            else if (le > b1) { b1 = le; i1 = e; }
        }
        float ex = expf(b1 - b0);
        float den = 1.f + ex;
        idx[t] = make_int2(i0, i1);
        gate[t] = make_float2(1.f / den, ex / den);
    }
}

// ---------------- routing ----------------
__global__ __launch_bounds__(256) void hist_kernel(const int2* __restrict__ idx, int* __restrict__ cnt) {
    int t = blockIdx.x * 256 + threadIdx.x;
    if (t < T_TOK) {
        int2 id = idx[t];
        atomicAdd(&cnt[id.x], 1);
        atomicAdd(&cnt[id.y], 1);
    }
}

__global__ void offsets_kernel(const int* __restrict__ cnt, int* __restrict__ asg) {
    if (threadIdx.x == 0 && blockIdx.x == 0) {
        int acc = 0;
        asg[0] = 0;
        for (int e = 0; e < 8; e++) { acc += (cnt[e] + 63) & ~63; asg[e + 1] = acc; }
    }
}

__global__ __launch_bounds__(256) void scatter_kernel(const int2* __restrict__ idx,
        const int* __restrict__ asg, int* __restrict__ cursor,
        int* __restrict__ list, int* __restrict__ pos) {
    int t = blockIdx.x * 256 + threadIdx.x;
    if (t >= T_TOK) return;
    int2 id = idx[t];
    int p0 = asg[id.x] + atomicAdd(&cursor[id.x], 1);
    list[p0] = t * 2;
    pos[t * 2] = p0;
    int p1 = asg[id.y] + atomicAdd(&cursor[id.y], 1);
    list[p1] = t * 2 + 1;
    pos[t * 2 + 1] = p1;
}

// ---------------- final: out = x1 + g0*y[p0] + g1*y[p1]  (f32 out) ----------------
__global__ __launch_bounds__(256) void final_kernel(const float* __restrict__ x1,
        const float* __restrict__ yp, const int* __restrict__ pos,
        const float2* __restrict__ gate, float* __restrict__ out) {
    int t = blockIdx.x, tid = threadIdx.x;
    float2 g = gate[t];
    int p0 = pos[t * 2], p1 = pos[t * 2 + 1];
#pragma unroll
    for (int i = 0; i < 3; i++) {
        int d = tid + i * 256;
        float y = g.x * yp[(size_t)p0 * 768 + d] + g.y * yp[(size_t)p1 * 768 + d];
        out[(size_t)t * 768 + d] = x1[(size_t)t * 768 + d] + y;
    }
}

extern "C" void kernel_launch(void* const* d_in, const int* in_sizes, int n_in,
                              void* d_out, int out_size, void* d_ws, size_t ws_size,
                              hipStream_t stream) {
    const float* x      = (const float*)d_in[0];
    const float* ln1_g  = (const float*)d_in[1];
    const float* ln1_b  = (const float*)d_in[2];
    const float* qkv_w  = (const float*)d_in[3];
    const float* qkv_b  = (const float*)d_in[4];
    const float* proj_w = (const float*)d_in[5];
    const float* proj_b = (const float*)d_in[6];
    const float* ln2_g  = (const float*)d_in[7];
    const float* ln2_b  = (const float*)d_in[8];
    const float* w_gate = (const float*)d_in[9];
    const float* w1     = (const float*)d_in[10];
    const float* b1     = (const float*)d_in[11];
    const float* w2     = (const float*)d_in[12];
    const float* b2     = (const float*)d_in[13];

    char* ws = (char*)d_ws;
    size_t off = 0;
    auto alloc = [&](size_t bytes) { size_t cur = off; off = (off + bytes + 255) & ~(size_t)255; return cur; };
    // region0: h_hi|h_lo|qkvf|o_hi|o_lo (dead before MoE2) — reused as ypair
    u16*    h_hi  = (u16*)   (ws + alloc((size_t)T_TOK * 768 * 2));
    u16*    h_lo  = (u16*)   (ws + alloc((size_t)T_TOK * 768 * 2));
    float*  qkvf  = (float*) (ws + alloc((size_t)T_TOK * 2304 * 4));
    u16*    o_hi  = (u16*)   (ws + alloc((size_t)T_TOK * 768 * 2));
    u16*    o_lo  = (u16*)   (ws + alloc((size_t)T_TOK * 768 * 2));
    float*  ypair = (float*) ws;   // 6848*768*4 = 21.0MB <= region0 ~48MB
    float*  x1    = (float*) (ws + alloc((size_t)T_TOK * 768 * 4));
    u16*    flat  = (u16*)   (ws + alloc((size_t)T_TOK * 768 * 2));
    int2*   idx   = (int2*)  (ws + alloc((size_t)T_TOK * 8));
    float2* gate  = (float2*)(ws + alloc((size_t)T_TOK * 8));
    int*    cnt   = (int*)   (ws + alloc(64));     // cnt[8] + cursor[8]
    int*    cursor = cnt + 8;
    int*    asg   = (int*)   (ws + alloc(64));     // aligned_start[9]
    int*    list  = (int*)   (ws + alloc((size_t)LISTN * 4));
    int*    pos   = (int*)   (ws + alloc((size_t)T_TOK * 2 * 4));
    u16*    hid   = (u16*)   (ws + alloc((size_t)LISTN * 3072 * 2));

    hipMemsetAsync(cnt, 0, 64, stream);
    hipMemsetAsync(list, 0xFF, (size_t)LISTN * 4, stream);

    ln1_kernel<<<T_TOK, 256, 0, stream>>>(x, ln1_g, ln1_b, h_hi, h_lo);
    gemm_split<0><<<dim3(50, 36), 256, 0, stream>>>(h_hi, h_lo, qkv_w, qkv_b, qkvf, nullptr, T_TOK, 2304, 768);
    attn_kernel<<<dim3(50, 192), 256, 0, stream>>>(qkvf, o_hi, o_lo);
    gemm_split<1><<<dim3(50, 12), 256, 0, stream>>>(o_hi, o_lo, proj_w, proj_b, x1, x, T_TOK, 768, 768);
    ln2_gate_kernel<<<T_TOK, 256, 0, stream>>>(x1, ln2_g, ln2_b, w_gate, flat, idx, gate);
    hist_kernel<<<(T_TOK + 255) / 256, 256, 0, stream>>>(idx, cnt);
    offsets_kernel<<<1, 64, 0, stream>>>(cnt, asg);
    scatter_kernel<<<(T_TOK + 255) / 256, 256, 0, stream>>>(idx, asg, cursor, list, pos);
    gemm_kernel<2><<<dim3(107, 48), 256, 0, stream>>>(flat, w1, b1, hid, list, asg, LISTN, 3072, 768);
    gemm_kernel<3><<<dim3(107, 12), 256, 0, stream>>>(hid, w2, b2, ypair, list, asg, LISTN, 768, 3072);
    final_kernel<<<T_TOK, 256, 0, stream>>>(x1, ypair, pos, gate, (float*)d_out);
}

// Round 4
// 860.102 us; speedup vs baseline: 1.4838x; 1.4838x over previous
//
#include <hip/hip_runtime.h>
#include <math.h>

typedef unsigned short u16;
typedef unsigned int u32;
typedef float floatx4 __attribute__((ext_vector_type(4)));
typedef __bf16 bf16x8 __attribute__((ext_vector_type(8)));

#define T_TOK 3152      // B*L = 16*197
#define SEQ 197
#define NH 12
#define LISTN 6848      // 107 tiles * 64 (worst-case aligned expert segments)

__device__ __forceinline__ float bf2f(u16 u) { return __uint_as_float(((u32)u) << 16); }
__device__ __forceinline__ u16 f2bf(float f) {
    u32 u = __float_as_uint(f);
    u += 0x7FFFu + ((u >> 16) & 1u);   // RNE
    return (u16)(u >> 16);
}
__device__ __forceinline__ float wred_sum(float v) {
#pragma unroll
    for (int off = 32; off; off >>= 1) v += __shfl_xor(v, off);
    return v;
}

// ---------------- LN1: h = LN(x)*g+b, split to bf16 hi/lo planes ----------------
__global__ __launch_bounds__(256) void ln1_kernel(const float* __restrict__ x,
        const float* __restrict__ g, const float* __restrict__ b,
        u16* __restrict__ h_hi, u16* __restrict__ h_lo) {
    int t = blockIdx.x, tid = threadIdx.x;
    int w = tid >> 6, lane = tid & 63;
    float v[3];
#pragma unroll
    for (int i = 0; i < 3; i++) v[i] = x[(size_t)t * 768 + tid + i * 256];
    float s = v[0] + v[1] + v[2];
    float q = v[0] * v[0] + v[1] * v[1] + v[2] * v[2];
    s = wred_sum(s); q = wred_sum(q);
    __shared__ float red[8];
    if (lane == 0) { red[w] = s; red[4 + w] = q; }
    __syncthreads();
    float st = red[0] + red[1] + red[2] + red[3];
    float qt = red[4] + red[5] + red[6] + red[7];
    float mean = st * (1.f / 768.f);
    float var = qt * (1.f / 768.f) - mean * mean;
    float rs = rsqrtf(var + 1e-5f);
#pragma unroll
    for (int i = 0; i < 3; i++) {
        int d = tid + i * 256;
        float hv = (v[i] - mean) * rs * g[d] + b[d];
        u16 hi = f2bf(hv);
        h_hi[(size_t)t * 768 + d] = hi;
        h_lo[(size_t)t * 768 + d] = f2bf(hv - bf2f(hi));
    }
}

// ---------------- split-bf16 GEMM (f32-grade): C = (Ah+Al)@(Bh+Bl) + bias ----------------
// SMODE 0: qkv   C(f32)[M,N] = A@B + bias
// SMODE 1: proj  C(f32)[M,N] = A@B + bias + resid
template <int SMODE>
__global__ __launch_bounds__(256) void gemm_split(const u16* __restrict__ Ah,
        const u16* __restrict__ Al, const float* __restrict__ B,
        const float* __restrict__ bias, float* __restrict__ C,
        const float* __restrict__ resid, int M, int N, int K) {
    int m0 = blockIdx.x * 64, n0 = blockIdx.y * 64;
    __shared__ u16 Ash[64 * 40], Asl[64 * 40];   // [m][k], stride 40
    __shared__ u16 Bsh[64 * 40], Bsl[64 * 40];   // transposed [n][k], stride 40
    int tid = threadIdx.x;
    int w = tid >> 6, lane = tid & 63, l15 = lane & 15, quad = lane >> 4;
    int arow = tid >> 2, acol = (tid & 3) * 8;
    int brow = tid >> 3, bcol = (tid & 7) * 8;

    const u16* ahp = nullptr;
    const u16* alp = nullptr;
    if (m0 + arow < M) {
        ahp = Ah + (size_t)(m0 + arow) * K;
        alp = Al + (size_t)(m0 + arow) * K;
    }

    floatx4 acc[4];
#pragma unroll
    for (int s = 0; s < 4; s++) acc[s] = (floatx4){0.f, 0.f, 0.f, 0.f};

    for (int k0 = 0; k0 < K; k0 += 32) {
        uint4 avh = make_uint4(0, 0, 0, 0), avl = make_uint4(0, 0, 0, 0);
        if (ahp) { avh = *(const uint4*)(ahp + k0 + acol); avl = *(const uint4*)(alp + k0 + acol); }
        *(uint4*)&Ash[arow * 40 + acol] = avh;
        *(uint4*)&Asl[arow * 40 + acol] = avl;
        const float* bsrc = B + (size_t)(k0 + brow) * N + n0 + bcol;
        float4 bv0 = *(const float4*)(bsrc);
        float4 bv1 = *(const float4*)(bsrc + 4);
        float bf[8] = {bv0.x, bv0.y, bv0.z, bv0.w, bv1.x, bv1.y, bv1.z, bv1.w};
#pragma unroll
        for (int j = 0; j < 8; j++) {
            u16 hb = f2bf(bf[j]);
            Bsh[(bcol + j) * 40 + brow] = hb;
            Bsl[(bcol + j) * 40 + brow] = f2bf(bf[j] - bf2f(hb));
        }
        __syncthreads();
        bf16x8 afh = *(const bf16x8*)&Ash[(w * 16 + l15) * 40 + quad * 8];
        bf16x8 afl = *(const bf16x8*)&Asl[(w * 16 + l15) * 40 + quad * 8];
#pragma unroll
        for (int s = 0; s < 4; s++) {
            bf16x8 bfh = *(const bf16x8*)&Bsh[(s * 16 + l15) * 40 + quad * 8];
            bf16x8 bfl = *(const bf16x8*)&Bsl[(s * 16 + l15) * 40 + quad * 8];
            acc[s] = __builtin_amdgcn_mfma_f32_16x16x32_bf16(afl, bfh, acc[s], 0, 0, 0);
            acc[s] = __builtin_amdgcn_mfma_f32_16x16x32_bf16(afh, bfl, acc[s], 0, 0, 0);
            acc[s] = __builtin_amdgcn_mfma_f32_16x16x32_bf16(afh, bfh, acc[s], 0, 0, 0);
        }
        __syncthreads();
    }

#pragma unroll
    for (int s = 0; s < 4; s++) {
        int col = n0 + s * 16 + l15;
        float bb = bias[col];
#pragma unroll
        for (int r = 0; r < 4; r++) {
            int row = m0 + w * 16 + quad * 4 + r;
            if (row < M) {
                float v = acc[s][r] + bb;
                if (SMODE == 1) v += resid[(size_t)row * N + col];
                C[(size_t)row * N + col] = v;
            }
        }
    }
}

// ---------------- MoE bf16 GEMM ----------------
// MODE 2: moe1  C(bf16)[p,N] = gelu(gather(A)@B_e + bias_e)   (A gathered via list)
// MODE 3: moe2  C(f32) [p,N] = A@B_e + bias_e                 (gate applied later)
template <int MODE>
__global__ __launch_bounds__(256) void gemm_kernel(const u16* __restrict__ A,
        const float* __restrict__ B, const float* __restrict__ bias, void* __restrict__ Cv,
        const int* __restrict__ list, const int* __restrict__ asg, int M, int N, int K) {
    int m0 = blockIdx.x * 64, n0 = blockIdx.y * 64;
    int a8 = asg[8];
    if (m0 >= a8) return;
    int e = 0;
    while (m0 >= asg[e + 1]) ++e;    // uniform across block
    const float* Bp = B + (size_t)e * K * N;
    const float* bp = bias + (size_t)e * N;

    __shared__ u16 As[64 * 40];          // [m][k], stride 40
    __shared__ u16 Bs[64 * 40];          // transposed [n][k], stride 40
    int tid = threadIdx.x;
    int w = tid >> 6, lane = tid & 63, l15 = lane & 15, quad = lane >> 4;
    int arow = tid >> 2, acol = (tid & 3) * 8;
    int brow = tid >> 3, bcol = (tid & 7) * 8;

    const u16* arp = nullptr;
    if (MODE == 2) {
        int entry = list[m0 + arow];
        if (entry >= 0) arp = A + (size_t)(entry >> 1) * K;
    } else {
        arp = A + (size_t)(m0 + arow) * K;   // padding rows hold finite poison; store-guarded
    }

    floatx4 acc[4];
#pragma unroll
    for (int s = 0; s < 4; s++) acc[s] = (floatx4){0.f, 0.f, 0.f, 0.f};

    for (int k0 = 0; k0 < K; k0 += 32) {
        uint4 av = make_uint4(0, 0, 0, 0);
        if (arp) av = *(const uint4*)(arp + k0 + acol);
        *(uint4*)&As[arow * 40 + acol] = av;
        const float* bsrc = Bp + (size_t)(k0 + brow) * N + n0 + bcol;
        float4 bv0 = *(const float4*)(bsrc);
        float4 bv1 = *(const float4*)(bsrc + 4);
        float bf[8] = {bv0.x, bv0.y, bv0.z, bv0.w, bv1.x, bv1.y, bv1.z, bv1.w};
#pragma unroll
        for (int j = 0; j < 8; j++) Bs[(bcol + j) * 40 + brow] = f2bf(bf[j]);
        __syncthreads();
        bf16x8 af = *(const bf16x8*)&As[(w * 16 + l15) * 40 + quad * 8];
#pragma unroll
        for (int s = 0; s < 4; s++) {
            bf16x8 bfr = *(const bf16x8*)&Bs[(s * 16 + l15) * 40 + quad * 8];
            acc[s] = __builtin_amdgcn_mfma_f32_16x16x32_bf16(af, bfr, acc[s], 0, 0, 0);
        }
        __syncthreads();
    }

#pragma unroll
    for (int s = 0; s < 4; s++) {
        int col = n0 + s * 16 + l15;
        float bb = bp[col];
#pragma unroll
        for (int r = 0; r < 4; r++) {
            int row = m0 + w * 16 + quad * 4 + r;
            float v = acc[s][r] + bb;
            if (list[row] >= 0) {
                if (MODE == 2) {
                    float gv = 0.5f * v * (1.f + erff(v * 0.70710678118f));  // exact gelu
                    ((u16*)Cv)[(size_t)row * N + col] = f2bf(gv);
                } else {
                    ((float*)Cv)[(size_t)row * N + col] = v;
                }
            }
        }
    }
}

// ---------------- MFMA attention: block = (b, h, 64-q-tile), 4 waves ----------------
// Q held as A-frags (split hi/lo); K staged per 64-key tile (B-layout [key][d]);
// all 197 scores in C-frags -> exact softmax in regs; P round-trips LDS (A-layout),
// V staged transposed [d][key]; 3-chain split-bf16 MFMA everywhere (f32-grade).
__global__ __launch_bounds__(256) void attn_mfma_kernel(const float* __restrict__ qkv,
        u16* __restrict__ ohi, u16* __restrict__ olo) {
    int by = blockIdx.y;
    int b = by / NH, h = by % NH;
    int qbase = blockIdx.x * 64;
    int tid = threadIdx.x;
    int w = tid >> 6, lane = tid & 63, l15 = lane & 15, quad = lane >> 4;

    __shared__ u16 Qh[64 * 72], Ql[64 * 72];
    __shared__ u16 Sh[64 * 72], Sl[64 * 72];   // K tile, then V^T tile
    __shared__ u16 Ph[64 * 72], Pl[64 * 72];

    int srow = tid >> 2;              // staging row 0..63
    int scol = (tid & 3) * 16;        // staging col group

    // ---- stage Q (rows clamped; stores guarded later) ----
    {
        int qr = min(qbase + srow, SEQ - 1);
        const float* src = qkv + ((size_t)(b * SEQ + qr)) * 2304 + h * 64 + scol;
        u16 hv[16], lv[16];
#pragma unroll
        for (int i = 0; i < 4; i++) {
            float4 v = *(const float4*)(src + i * 4);
            float vv[4] = {v.x, v.y, v.z, v.w};
#pragma unroll
            for (int j = 0; j < 4; j++) {
                u16 hb = f2bf(vv[j]);
                hv[i * 4 + j] = hb;
                lv[i * 4 + j] = f2bf(vv[j] - bf2f(hb));
            }
        }
        int o = srow * 72 + scol;
        *(uint4*)&Qh[o] = *(const uint4*)&hv[0];
        *(uint4*)&Qh[o + 8] = *(const uint4*)&hv[8];
        *(uint4*)&Ql[o] = *(const uint4*)&lv[0];
        *(uint4*)&Ql[o + 8] = *(const uint4*)&lv[8];
    }
    __syncthreads();
    bf16x8 aqh[2], aql[2];
#pragma unroll
    for (int s2 = 0; s2 < 2; s2++) {
        aqh[s2] = *(const bf16x8*)&Qh[(w * 16 + l15) * 72 + s2 * 32 + quad * 8];
        aql[s2] = *(const bf16x8*)&Ql[(w * 16 + l15) * 72 + s2 * 32 + quad * 8];
    }
    __syncthreads();

    // ---- scores: loop 4 key-tiles of 64 ----
    floatx4 sc[16];
#pragma unroll
    for (int f = 0; f < 16; f++) sc[f] = (floatx4){0.f, 0.f, 0.f, 0.f};

    for (int t = 0; t < 4; t++) {
        int key = t * 64 + srow;
        u16 hv[16], lv[16];
        if (key < SEQ) {
            const float* src = qkv + ((size_t)(b * SEQ + key)) * 2304 + 768 + h * 64 + scol;
#pragma unroll
            for (int i = 0; i < 4; i++) {
                float4 v = *(const float4*)(src + i * 4);
                float vv[4] = {v.x, v.y, v.z, v.w};
#pragma unroll
                for (int j = 0; j < 4; j++) {
                    u16 hb = f2bf(vv[j]);
                    hv[i * 4 + j] = hb;
                    lv[i * 4 + j] = f2bf(vv[j] - bf2f(hb));
                }
            }
        } else {
#pragma unroll
            for (int i = 0; i < 16; i++) { hv[i] = 0; lv[i] = 0; }
        }
        int o = srow * 72 + scol;
        *(uint4*)&Sh[o] = *(const uint4*)&hv[0];
        *(uint4*)&Sh[o + 8] = *(const uint4*)&hv[8];
        *(uint4*)&Sl[o] = *(const uint4*)&lv[0];
        *(uint4*)&Sl[o + 8] = *(const uint4*)&lv[8];
        __syncthreads();
#pragma unroll
        for (int s = 0; s < 4; s++) {
#pragma unroll
            for (int s2 = 0; s2 < 2; s2++) {
                bf16x8 bkh = *(const bf16x8*)&Sh[(s * 16 + l15) * 72 + s2 * 32 + quad * 8];
                bf16x8 bkl = *(const bf16x8*)&Sl[(s * 16 + l15) * 72 + s2 * 32 + quad * 8];
                sc[t * 4 + s] = __builtin_amdgcn_mfma_f32_16x16x32_bf16(aql[s2], bkh, sc[t * 4 + s], 0, 0, 0);
                sc[t * 4 + s] = __builtin_amdgcn_mfma_f32_16x16x32_bf16(aqh[s2], bkl, sc[t * 4 + s], 0, 0, 0);
                sc[t * 4 + s] = __builtin_amdgcn_mfma_f32_16x16x32_bf16(aqh[s2], bkh, sc[t * 4 + s], 0, 0, 0);
            }
        }
        __syncthreads();
    }

    // ---- exact softmax in registers (C layout: row q=quad*4+r, col key=f-derived) ----
    float m[4] = {-1e30f, -1e30f, -1e30f, -1e30f};
#pragma unroll
    for (int f = 0; f < 16; f++) {
        int key = (f >> 2) * 64 + (f & 3) * 16 + l15;
        bool valid = key < SEQ;
#pragma unroll
        for (int r = 0; r < 4; r++) {
            float s = valid ? sc[f][r] * 0.125f : -1e30f;
            sc[f][r] = s;
            m[r] = fmaxf(m[r], s);
        }
    }
#pragma unroll
    for (int r = 0; r < 4; r++) {
#pragma unroll
        for (int off = 1; off < 16; off <<= 1) m[r] = fmaxf(m[r], __shfl_xor(m[r], off));
    }
    float sum[4] = {0.f, 0.f, 0.f, 0.f};
#pragma unroll
    for (int f = 0; f < 16; f++) {
#pragma unroll
        for (int r = 0; r < 4; r++) {
            float p = expf(sc[f][r] - m[r]);
            sc[f][r] = p;
            sum[r] += p;
        }
    }
    float inv[4];
#pragma unroll
    for (int r = 0; r < 4; r++) {
#pragma unroll
        for (int off = 1; off < 16; off <<= 1) sum[r] += __shfl_xor(sum[r], off);
        inv[r] = 1.f / sum[r];
    }

    // ---- PV: loop 4 key-tiles; P->LDS (A-layout), V->LDS transposed [d][key] ----
    floatx4 oacc[4];
#pragma unroll
    for (int sd = 0; sd < 4; sd++) oacc[sd] = (floatx4){0.f, 0.f, 0.f, 0.f};

    for (int t = 0; t < 4; t++) {
        // write P tile (rows w*16.., cols = key-in-tile)
#pragma unroll
        for (int s = 0; s < 4; s++) {
#pragma unroll
            for (int r = 0; r < 4; r++) {
                float p = sc[t * 4 + s][r];
                u16 hb = f2bf(p);
                int row = w * 16 + quad * 4 + r;
                Ph[row * 72 + s * 16 + l15] = hb;
                Pl[row * 72 + s * 16 + l15] = f2bf(p - bf2f(hb));
            }
        }
        // stage V tile transposed: Sh/Sl[d][key_local]
        {
            int key = t * 64 + srow;
            float vv[16];
            if (key < SEQ) {
                const float* src = qkv + ((size_t)(b * SEQ + key)) * 2304 + 1536 + h * 64 + scol;
#pragma unroll
                for (int i = 0; i < 4; i++) {
                    float4 v = *(const float4*)(src + i * 4);
                    vv[i * 4 + 0] = v.x; vv[i * 4 + 1] = v.y; vv[i * 4 + 2] = v.z; vv[i * 4 + 3] = v.w;
                }
            } else {
#pragma unroll
                for (int i = 0; i < 16; i++) vv[i] = 0.f;
            }
#pragma unroll
            for (int i = 0; i < 16; i++) {
                u16 hb = f2bf(vv[i]);
                Sh[(scol + i) * 72 + srow] = hb;
                Sl[(scol + i) * 72 + srow] = f2bf(vv[i] - bf2f(hb));
            }
        }
        __syncthreads();
#pragma unroll
        for (int s2 = 0; s2 < 2; s2++) {
            bf16x8 aph = *(const bf16x8*)&Ph[(w * 16 + l15) * 72 + s2 * 32 + quad * 8];
            bf16x8 apl = *(const bf16x8*)&Pl[(w * 16 + l15) * 72 + s2 * 32 + quad * 8];
#pragma unroll
            for (int sd = 0; sd < 4; sd++) {
                bf16x8 bvh = *(const bf16x8*)&Sh[(sd * 16 + l15) * 72 + s2 * 32 + quad * 8];
                bf16x8 bvl = *(const bf16x8*)&Sl[(sd * 16 + l15) * 72 + s2 * 32 + quad * 8];
                oacc[sd] = __builtin_amdgcn_mfma_f32_16x16x32_bf16(apl, bvh, oacc[sd], 0, 0, 0);
                oacc[sd] = __builtin_amdgcn_mfma_f32_16x16x32_bf16(aph, bvl, oacc[sd], 0, 0, 0);
                oacc[sd] = __builtin_amdgcn_mfma_f32_16x16x32_bf16(aph, bvh, oacc[sd], 0, 0, 0);
            }
        }
        __syncthreads();
    }

    // ---- epilogue: o/sum, split hi/lo ----
#pragma unroll
    for (int sd = 0; sd < 4; sd++) {
#pragma unroll
        for (int r = 0; r < 4; r++) {
            int q = qbase + w * 16 + quad * 4 + r;
            if (q < SEQ) {
                float val = oacc[sd][r] * inv[r];
                u16 hb = f2bf(val);
                size_t o = ((size_t)(b * SEQ + q)) * 768 + h * 64 + sd * 16 + l15;
                ohi[o] = hb;
                olo[o] = f2bf(val - bf2f(hb));
            }
        }
    }
}

// ---------------- LN2 + gate (top-2 of 8) ----------------
__global__ __launch_bounds__(256) void ln2_gate_kernel(const float* __restrict__ x1,
        const float* __restrict__ g, const float* __restrict__ b, const float* __restrict__ wg,
        u16* __restrict__ flat, int2* __restrict__ idx, float2* __restrict__ gate) {
    int t = blockIdx.x, tid = threadIdx.x;
    int w = tid >> 6, lane = tid & 63;
    float v[3];
#pragma unroll
    for (int i = 0; i < 3; i++) v[i] = x1[(size_t)t * 768 + tid + i * 256];
    float s = v[0] + v[1] + v[2];
    float q = v[0] * v[0] + v[1] * v[1] + v[2] * v[2];
    s = wred_sum(s); q = wred_sum(q);
    __shared__ float red[8];
    __shared__ float fs[768];
    __shared__ float lg[8];
    if (lane == 0) { red[w] = s; red[4 + w] = q; }
    __syncthreads();
    float st = red[0] + red[1] + red[2] + red[3];
    float qt = red[4] + red[5] + red[6] + red[7];
    float mean = st * (1.f / 768.f);
    float var = qt * (1.f / 768.f) - mean * mean;
    float rs = rsqrtf(var + 1e-5f);
#pragma unroll
    for (int i = 0; i < 3; i++) {
        int d = tid + i * 256;
        float f = (v[i] - mean) * rs * g[d] + b[d];
        flat[(size_t)t * 768 + d] = f2bf(f);
        fs[d] = f;
    }
    __syncthreads();
    int e0 = 2 * w, e1 = 2 * w + 1;
    float p0 = 0.f, p1 = 0.f;
    for (int d = lane; d < 768; d += 64) {
        float f = fs[d];
        p0 += f * wg[d * 8 + e0];
        p1 += f * wg[d * 8 + e1];
    }
    p0 = wred_sum(p0); p1 = wred_sum(p1);
    if (lane == 0) { lg[e0] = p0; lg[e1] = p1; }
    __syncthreads();
    if (tid == 0) {
        float b0 = -1e30f, b1 = -1e30f;
        int i0 = 0, i1 = 0;
        for (int e = 0; e < 8; e++) {     // strict > keeps first occurrence (jax tie-break)
            float le = lg[e];
            if (le > b0) { b1 = b0; i1 = i0; b0 = le; i0 = e; }
            else if (le > b1) { b1 = le; i1 = e; }
        }
        float ex = expf(b1 - b0);
        float den = 1.f + ex;
        idx[t] = make_int2(i0, i1);
        gate[t] = make_float2(1.f / den, ex / den);
    }
}

// ---------------- routing ----------------
__global__ __launch_bounds__(256) void hist_kernel(const int2* __restrict__ idx, int* __restrict__ cnt) {
    int t = blockIdx.x * 256 + threadIdx.x;
    if (t < T_TOK) {
        int2 id = idx[t];
        atomicAdd(&cnt[id.x], 1);
        atomicAdd(&cnt[id.y], 1);
    }
}

__global__ void offsets_kernel(const int* __restrict__ cnt, int* __restrict__ asg) {
    if (threadIdx.x == 0 && blockIdx.x == 0) {
        int acc = 0;
        asg[0] = 0;
        for (int e = 0; e < 8; e++) { acc += (cnt[e] + 63) & ~63; asg[e + 1] = acc; }
    }
}

__global__ __launch_bounds__(256) void scatter_kernel(const int2* __restrict__ idx,
        const int* __restrict__ asg, int* __restrict__ cursor,
        int* __restrict__ list, int* __restrict__ pos) {
    int t = blockIdx.x * 256 + threadIdx.x;
    if (t >= T_TOK) return;
    int2 id = idx[t];
    int p0 = asg[id.x] + atomicAdd(&cursor[id.x], 1);
    list[p0] = t * 2;
    pos[t * 2] = p0;
    int p1 = asg[id.y] + atomicAdd(&cursor[id.y], 1);
    list[p1] = t * 2 + 1;
    pos[t * 2 + 1] = p1;
}

// ---------------- final: out = x1 + g0*y[p0] + g1*y[p1]  (f32 out) ----------------
__global__ __launch_bounds__(256) void final_kernel(const float* __restrict__ x1,
        const float* __restrict__ yp, const int* __restrict__ pos,
        const float2* __restrict__ gate, float* __restrict__ out) {
    int t = blockIdx.x, tid = threadIdx.x;
    float2 g = gate[t];
    int p0 = pos[t * 2], p1 = pos[t * 2 + 1];
#pragma unroll
    for (int i = 0; i < 3; i++) {
        int d = tid + i * 256;
        float y = g.x * yp[(size_t)p0 * 768 + d] + g.y * yp[(size_t)p1 * 768 + d];
        out[(size_t)t * 768 + d] = x1[(size_t)t * 768 + d] + y;
    }
}

extern "C" void kernel_launch(void* const* d_in, const int* in_sizes, int n_in,
                              void* d_out, int out_size, void* d_ws, size_t ws_size,
                              hipStream_t stream) {
    const float* x      = (const float*)d_in[0];
    const float* ln1_g  = (const float*)d_in[1];
    const float* ln1_b  = (const float*)d_in[2];
    const float* qkv_w  = (const float*)d_in[3];
    const float* qkv_b  = (const float*)d_in[4];
    const float* proj_w = (const float*)d_in[5];
    const float* proj_b = (const float*)d_in[6];
    const float* ln2_g  = (const float*)d_in[7];
    const float* ln2_b  = (const float*)d_in[8];
    const float* w_gate = (const float*)d_in[9];
    const float* w1     = (const float*)d_in[10];
    const float* b1     = (const float*)d_in[11];
    const float* w2     = (const float*)d_in[12];
    const float* b2     = (const float*)d_in[13];

    char* ws = (char*)d_ws;
    size_t off = 0;
    auto alloc = [&](size_t bytes) { size_t cur = off; off = (off + bytes + 255) & ~(size_t)255; return cur; };
    // region0: h_hi|h_lo|qkvf|o_hi|o_lo (dead before MoE2) — reused as ypair
    u16*    h_hi  = (u16*)   (ws + alloc((size_t)T_TOK * 768 * 2));
    u16*    h_lo  = (u16*)   (ws + alloc((size_t)T_TOK * 768 * 2));
    float*  qkvf  = (float*) (ws + alloc((size_t)T_TOK * 2304 * 4));
    u16*    o_hi  = (u16*)   (ws + alloc((size_t)T_TOK * 768 * 2));
    u16*    o_lo  = (u16*)   (ws + alloc((size_t)T_TOK * 768 * 2));
    float*  ypair = (float*) ws;   // 6848*768*4 = 21.0MB <= region0 ~48MB
    float*  x1    = (float*) (ws + alloc((size_t)T_TOK * 768 * 4));
    u16*    flat  = (u16*)   (ws + alloc((size_t)T_TOK * 768 * 2));
    int2*   idx   = (int2*)  (ws + alloc((size_t)T_TOK * 8));
    float2* gate  = (float2*)(ws + alloc((size_t)T_TOK * 8));
    int*    cnt   = (int*)   (ws + alloc(64));     // cnt[8] + cursor[8]
    int*    cursor = cnt + 8;
    int*    asg   = (int*)   (ws + alloc(64));     // aligned_start[9]
    int*    list  = (int*)   (ws + alloc((size_t)LISTN * 4));
    int*    pos   = (int*)   (ws + alloc((size_t)T_TOK * 2 * 4));
    u16*    hid   = (u16*)   (ws + alloc((size_t)LISTN * 3072 * 2));

    hipMemsetAsync(cnt, 0, 64, stream);
    hipMemsetAsync(list, 0xFF, (size_t)LISTN * 4, stream);

    ln1_kernel<<<T_TOK, 256, 0, stream>>>(x, ln1_g, ln1_b, h_hi, h_lo);
    gemm_split<0><<<dim3(50, 36), 256, 0, stream>>>(h_hi, h_lo, qkv_w, qkv_b, qkvf, nullptr, T_TOK, 2304, 768);
    attn_mfma_kernel<<<dim3(4, 192), 256, 0, stream>>>(qkvf, o_hi, o_lo);
    gemm_split<1><<<dim3(50, 12), 256, 0, stream>>>(o_hi, o_lo, proj_w, proj_b, x1, x, T_TOK, 768, 768);
    ln2_gate_kernel<<<T_TOK, 256, 0, stream>>>(x1, ln2_g, ln2_b, w_gate, flat, idx, gate);
    hist_kernel<<<(T_TOK + 255) / 256, 256, 0, stream>>>(idx, cnt);
    offsets_kernel<<<1, 64, 0, stream>>>(cnt, asg);
    scatter_kernel<<<(T_TOK + 255) / 256, 256, 0, stream>>>(idx, asg, cursor, list, pos);
    gemm_kernel<2><<<dim3(107, 48), 256, 0, stream>>>(flat, w1, b1, hid, list, asg, LISTN, 3072, 768);
    gemm_kernel<3><<<dim3(107, 12), 256, 0, stream>>>(hid, w2, b2, ypair, list, asg, LISTN, 768, 3072);
    final_kernel<<<T_TOK, 256, 0, stream>>>(x1, ypair, pos, gate, (float*)d_out);
}

// Round 5
// 676.306 us; speedup vs baseline: 1.8871x; 1.2718x over previous
//
#include <hip/hip_runtime.h>
#include <math.h>

typedef unsigned short u16;
typedef unsigned int u32;
typedef float floatx4 __attribute__((ext_vector_type(4)));
typedef __bf16 bf16x8 __attribute__((ext_vector_type(8)));

#define T_TOK 3152      // B*L = 16*197
#define SEQ 197
#define NH 12
#define LISTN 7424      // 58 tiles * 128 (worst-case 128-aligned expert segments)
#define MOE_MT 58

__device__ __forceinline__ float bf2f(u16 u) { return __uint_as_float(((u32)u) << 16); }
__device__ __forceinline__ u16 f2bf(float f) {
    u32 u = __float_as_uint(f);
    u += 0x7FFFu + ((u >> 16) & 1u);   // RNE
    return (u16)(u >> 16);
}
__device__ __forceinline__ float wred_sum(float v) {
#pragma unroll
    for (int off = 32; off; off >>= 1) v += __shfl_xor(v, off);
    return v;
}

// ---------------- weight prep: in f32 [z][R][C] -> out bf16 [z][C][R] (opt split hi/lo) ----------------
template <int SPLIT>
__global__ __launch_bounds__(256) void transp_kernel(const float* __restrict__ in,
        u16* __restrict__ oh, u16* __restrict__ ol, int R, int C) {
    int r0 = blockIdx.x * 64, c0 = blockIdx.y * 64;
    size_t zo = (size_t)blockIdx.z * R * C;
    __shared__ float Lt[64][68];
    int tid = threadIdx.x;
    int rr = tid >> 2, cs = (tid & 3) * 16;
    const float* src = in + zo + (size_t)(r0 + rr) * C + c0 + cs;
#pragma unroll
    for (int i = 0; i < 4; i++) *(float4*)&Lt[rr][cs + i * 4] = *(const float4*)(src + i * 4);
    __syncthreads();
    int cw = tid >> 2, rs = (tid & 3) * 16;
    u16 hv[16], lv[16];
#pragma unroll
    for (int j = 0; j < 16; j++) {
        float v = Lt[rs + j][cw];
        u16 hb = f2bf(v);
        hv[j] = hb;
        if (SPLIT) lv[j] = f2bf(v - bf2f(hb));
    }
    u16* dst = oh + zo + (size_t)(c0 + cw) * R + r0 + rs;
    *(uint4*)dst = *(const uint4*)&hv[0];
    *(uint4*)(dst + 8) = *(const uint4*)&hv[8];
    if (SPLIT) {
        u16* dstl = ol + zo + (size_t)(c0 + cw) * R + r0 + rs;
        *(uint4*)dstl = *(const uint4*)&lv[0];
        *(uint4*)(dstl + 8) = *(const uint4*)&lv[8];
    }
}

// ---------------- LN1: h = LN(x)*g+b, split to bf16 hi/lo planes ----------------
__global__ __launch_bounds__(256) void ln1_kernel(const float* __restrict__ x,
        const float* __restrict__ g, const float* __restrict__ b,
        u16* __restrict__ h_hi, u16* __restrict__ h_lo) {
    int t = blockIdx.x, tid = threadIdx.x;
    int w = tid >> 6, lane = tid & 63;
    float v[3];
#pragma unroll
    for (int i = 0; i < 3; i++) v[i] = x[(size_t)t * 768 + tid + i * 256];
    float s = v[0] + v[1] + v[2];
    float q = v[0] * v[0] + v[1] * v[1] + v[2] * v[2];
    s = wred_sum(s); q = wred_sum(q);
    __shared__ float red[8];
    if (lane == 0) { red[w] = s; red[4 + w] = q; }
    __syncthreads();
    float st = red[0] + red[1] + red[2] + red[3];
    float qt = red[4] + red[5] + red[6] + red[7];
    float mean = st * (1.f / 768.f);
    float var = qt * (1.f / 768.f) - mean * mean;
    float rs = rsqrtf(var + 1e-5f);
#pragma unroll
    for (int i = 0; i < 3; i++) {
        int d = tid + i * 256;
        float hv = (v[i] - mean) * rs * g[d] + b[d];
        u16 hi = f2bf(hv);
        h_hi[(size_t)t * 768 + d] = hi;
        h_lo[(size_t)t * 768 + d] = f2bf(hv - bf2f(hi));
    }
}

// ---------------- unified 128x128 MFMA GEMM ----------------
// B is pre-transposed bf16 [n][k]. MODE 0: qkv split->f32. MODE 1: proj split + resid -> f32.
// MODE 2: moe1 gathered A, gelu -> bf16. MODE 3: moe2 dense A -> f32.
template <int MODE>
__global__ __launch_bounds__(256) void gemm128(const u16* __restrict__ Ah,
        const u16* __restrict__ Al, const u16* __restrict__ Bh, const u16* __restrict__ Bl,
        const float* __restrict__ bias, void* __restrict__ Cv, const float* __restrict__ resid,
        const int* __restrict__ list, const int* __restrict__ asg, int M, int N, int K) {
    constexpr bool SPLIT = (MODE <= 1);
    int m0 = blockIdx.x * 128, n0 = blockIdx.y * 128;
    const u16* Bph = Bh;
    const u16* Bpl = Bl;
    const float* bp = bias;
    if (MODE >= 2) {
        if (m0 >= asg[8]) return;
        int e = 0;
        while (m0 >= asg[e + 1]) ++e;    // uniform across block
        Bph = Bh + (size_t)e * N * K;
        bp = bias + (size_t)e * N;
    }
    __shared__ u16 Ash[128 * 40];
    __shared__ u16 Bsh[128 * 40];
    __shared__ u16 Asl[SPLIT ? 128 * 40 : 64];
    __shared__ u16 Bsl[SPLIT ? 128 * 40 : 64];

    int tid = threadIdx.x;
    int w = tid >> 6, lane = tid & 63, l15 = lane & 15, quad = lane >> 4;
    int wm = (w & 1) * 64, wn = (w >> 1) * 64;
    int srow = tid >> 2, scol = (tid & 3) * 8;

    const u16* ahp[2];
    const u16* alp[2];
#pragma unroll
    for (int it = 0; it < 2; it++) {
        int row = m0 + srow + it * 64;
        if (MODE == 2) {
            int entry = list[row];
            ahp[it] = (entry >= 0) ? Ah + (size_t)(entry >> 1) * K : nullptr;
        } else if (MODE == 3) {
            ahp[it] = Ah + (size_t)row * K;   // padding rows finite poison; store-guarded
        } else {
            int rc = min(row, M - 1);
            ahp[it] = Ah + (size_t)rc * K;
            alp[it] = Al + (size_t)rc * K;
        }
    }

    floatx4 acc[4][4];
#pragma unroll
    for (int mi = 0; mi < 4; mi++)
#pragma unroll
        for (int ni = 0; ni < 4; ni++) acc[mi][ni] = (floatx4){0.f, 0.f, 0.f, 0.f};

    for (int k0 = 0; k0 < K; k0 += 32) {
#pragma unroll
        for (int it = 0; it < 2; it++) {
            int r = srow + it * 64;
            uint4 av = make_uint4(0, 0, 0, 0);
            if (MODE != 2 || ahp[it]) av = *(const uint4*)(ahp[it] + k0 + scol);
            *(uint4*)&Ash[r * 40 + scol] = av;
            if (SPLIT) *(uint4*)&Asl[r * 40 + scol] = *(const uint4*)(alp[it] + k0 + scol);
            *(uint4*)&Bsh[r * 40 + scol] = *(const uint4*)(Bph + (size_t)(n0 + r) * K + k0 + scol);
            if (SPLIT) *(uint4*)&Bsl[r * 40 + scol] = *(const uint4*)(Bpl + (size_t)(n0 + r) * K + k0 + scol);
        }
        __syncthreads();
        bf16x8 afh[4], bfh[4], afl[4], bfl[4];
#pragma unroll
        for (int i = 0; i < 4; i++) {
            afh[i] = *(const bf16x8*)&Ash[(wm + i * 16 + l15) * 40 + quad * 8];
            bfh[i] = *(const bf16x8*)&Bsh[(wn + i * 16 + l15) * 40 + quad * 8];
            if (SPLIT) {
                afl[i] = *(const bf16x8*)&Asl[(wm + i * 16 + l15) * 40 + quad * 8];
                bfl[i] = *(const bf16x8*)&Bsl[(wn + i * 16 + l15) * 40 + quad * 8];
            }
        }
#pragma unroll
        for (int mi = 0; mi < 4; mi++)
#pragma unroll
            for (int ni = 0; ni < 4; ni++) {
                if (SPLIT) {
                    acc[mi][ni] = __builtin_amdgcn_mfma_f32_16x16x32_bf16(afl[mi], bfh[ni], acc[mi][ni], 0, 0, 0);
                    acc[mi][ni] = __builtin_amdgcn_mfma_f32_16x16x32_bf16(afh[mi], bfl[ni], acc[mi][ni], 0, 0, 0);
                }
                acc[mi][ni] = __builtin_amdgcn_mfma_f32_16x16x32_bf16(afh[mi], bfh[ni], acc[mi][ni], 0, 0, 0);
            }
        __syncthreads();
    }

#pragma unroll
    for (int ni = 0; ni < 4; ni++) {
        int col = n0 + wn + ni * 16 + l15;
        float bb = bp[col];
#pragma unroll
        for (int mi = 0; mi < 4; mi++) {
#pragma unroll
            for (int r = 0; r < 4; r++) {
                int row = m0 + wm + mi * 16 + quad * 4 + r;
                float v = acc[mi][ni][r] + bb;
                if (MODE == 0) {
                    if (row < M) ((float*)Cv)[(size_t)row * N + col] = v;
                } else if (MODE == 1) {
                    if (row < M) ((float*)Cv)[(size_t)row * N + col] = v + resid[(size_t)row * N + col];
                } else if (MODE == 2) {
                    if (list[row] >= 0) {
                        float gv = 0.5f * v * (1.f + erff(v * 0.70710678118f));  // exact gelu
                        ((u16*)Cv)[(size_t)row * N + col] = f2bf(gv);
                    }
                } else {
                    if (list[row] >= 0) ((float*)Cv)[(size_t)row * N + col] = v;
                }
            }
        }
    }
}

// ---------------- MFMA attention: block = (b, h, 64-q-tile), 4 waves ----------------
__global__ __launch_bounds__(256) void attn_mfma_kernel(const float* __restrict__ qkv,
        u16* __restrict__ ohi, u16* __restrict__ olo) {
    int by = blockIdx.y;
    int b = by / NH, h = by % NH;
    int qbase = blockIdx.x * 64;
    int tid = threadIdx.x;
    int w = tid >> 6, lane = tid & 63, l15 = lane & 15, quad = lane >> 4;

    __shared__ u16 Qh[64 * 72], Ql[64 * 72];
    __shared__ u16 Sh[64 * 72], Sl[64 * 72];   // K tile, then V^T tile
    __shared__ u16 Ph[64 * 72], Pl[64 * 72];

    int srow = tid >> 2;
    int scol = (tid & 3) * 16;

    {
        int qr = min(qbase + srow, SEQ - 1);
        const float* src = qkv + ((size_t)(b * SEQ + qr)) * 2304 + h * 64 + scol;
        u16 hv[16], lv[16];
#pragma unroll
        for (int i = 0; i < 4; i++) {
            float4 v = *(const float4*)(src + i * 4);
            float vv[4] = {v.x, v.y, v.z, v.w};
#pragma unroll
            for (int j = 0; j < 4; j++) {
                u16 hb = f2bf(vv[j]);
                hv[i * 4 + j] = hb;
                lv[i * 4 + j] = f2bf(vv[j] - bf2f(hb));
            }
        }
        int o = srow * 72 + scol;
        *(uint4*)&Qh[o] = *(const uint4*)&hv[0];
        *(uint4*)&Qh[o + 8] = *(const uint4*)&hv[8];
        *(uint4*)&Ql[o] = *(const uint4*)&lv[0];
        *(uint4*)&Ql[o + 8] = *(const uint4*)&lv[8];
    }
    __syncthreads();
    bf16x8 aqh[2], aql[2];
#pragma unroll
    for (int s2 = 0; s2 < 2; s2++) {
        aqh[s2] = *(const bf16x8*)&Qh[(w * 16 + l15) * 72 + s2 * 32 + quad * 8];
        aql[s2] = *(const bf16x8*)&Ql[(w * 16 + l15) * 72 + s2 * 32 + quad * 8];
    }
    __syncthreads();

    floatx4 sc[16];
#pragma unroll
    for (int f = 0; f < 16; f++) sc[f] = (floatx4){0.f, 0.f, 0.f, 0.f};

    for (int t = 0; t < 4; t++) {
        int key = t * 64 + srow;
        u16 hv[16], lv[16];
        if (key < SEQ) {
            const float* src = qkv + ((size_t)(b * SEQ + key)) * 2304 + 768 + h * 64 + scol;
#pragma unroll
            for (int i = 0; i < 4; i++) {
                float4 v = *(const float4*)(src + i * 4);
                float vv[4] = {v.x, v.y, v.z, v.w};
#pragma unroll
                for (int j = 0; j < 4; j++) {
                    u16 hb = f2bf(vv[j]);
                    hv[i * 4 + j] = hb;
                    lv[i * 4 + j] = f2bf(vv[j] - bf2f(hb));
                }
            }
        } else {
#pragma unroll
            for (int i = 0; i < 16; i++) { hv[i] = 0; lv[i] = 0; }
        }
        int o = srow * 72 + scol;
        *(uint4*)&Sh[o] = *(const uint4*)&hv[0];
        *(uint4*)&Sh[o + 8] = *(const uint4*)&hv[8];
        *(uint4*)&Sl[o] = *(const uint4*)&lv[0];
        *(uint4*)&Sl[o + 8] = *(const uint4*)&lv[8];
        __syncthreads();
#pragma unroll
        for (int s = 0; s < 4; s++) {
#pragma unroll
            for (int s2 = 0; s2 < 2; s2++) {
                bf16x8 bkh = *(const bf16x8*)&Sh[(s * 16 + l15) * 72 + s2 * 32 + quad * 8];
                bf16x8 bkl = *(const bf16x8*)&Sl[(s * 16 + l15) * 72 + s2 * 32 + quad * 8];
                sc[t * 4 + s] = __builtin_amdgcn_mfma_f32_16x16x32_bf16(aql[s2], bkh, sc[t * 4 + s], 0, 0, 0);
                sc[t * 4 + s] = __builtin_amdgcn_mfma_f32_16x16x32_bf16(aqh[s2], bkl, sc[t * 4 + s], 0, 0, 0);
                sc[t * 4 + s] = __builtin_amdgcn_mfma_f32_16x16x32_bf16(aqh[s2], bkh, sc[t * 4 + s], 0, 0, 0);
            }
        }
        __syncthreads();
    }

    float m[4] = {-1e30f, -1e30f, -1e30f, -1e30f};
#pragma unroll
    for (int f = 0; f < 16; f++) {
        int key = (f >> 2) * 64 + (f & 3) * 16 + l15;
        bool valid = key < SEQ;
#pragma unroll
        for (int r = 0; r < 4; r++) {
            float s = valid ? sc[f][r] * 0.125f : -1e30f;
            sc[f][r] = s;
            m[r] = fmaxf(m[r], s);
        }
    }
#pragma unroll
    for (int r = 0; r < 4; r++) {
#pragma unroll
        for (int off = 1; off < 16; off <<= 1) m[r] = fmaxf(m[r], __shfl_xor(m[r], off));
    }
    float sum[4] = {0.f, 0.f, 0.f, 0.f};
#pragma unroll
    for (int f = 0; f < 16; f++) {
#pragma unroll
        for (int r = 0; r < 4; r++) {
            float p = expf(sc[f][r] - m[r]);
            sc[f][r] = p;
            sum[r] += p;
        }
    }
    float inv[4];
#pragma unroll
    for (int r = 0; r < 4; r++) {
#pragma unroll
        for (int off = 1; off < 16; off <<= 1) sum[r] += __shfl_xor(sum[r], off);
        inv[r] = 1.f / sum[r];
    }

    floatx4 oacc[4];
#pragma unroll
    for (int sd = 0; sd < 4; sd++) oacc[sd] = (floatx4){0.f, 0.f, 0.f, 0.f};

    for (int t = 0; t < 4; t++) {
#pragma unroll
        for (int s = 0; s < 4; s++) {
#pragma unroll
            for (int r = 0; r < 4; r++) {
                float p = sc[t * 4 + s][r];
                u16 hb = f2bf(p);
                int row = w * 16 + quad * 4 + r;
                Ph[row * 72 + s * 16 + l15] = hb;
                Pl[row * 72 + s * 16 + l15] = f2bf(p - bf2f(hb));
            }
        }
        {
            int key = t * 64 + srow;
            float vv[16];
            if (key < SEQ) {
                const float* src = qkv + ((size_t)(b * SEQ + key)) * 2304 + 1536 + h * 64 + scol;
#pragma unroll
                for (int i = 0; i < 4; i++) {
                    float4 v = *(const float4*)(src + i * 4);
                    vv[i * 4 + 0] = v.x; vv[i * 4 + 1] = v.y; vv[i * 4 + 2] = v.z; vv[i * 4 + 3] = v.w;
                }
            } else {
#pragma unroll
                for (int i = 0; i < 16; i++) vv[i] = 0.f;
            }
#pragma unroll
            for (int i = 0; i < 16; i++) {
                u16 hb = f2bf(vv[i]);
                Sh[(scol + i) * 72 + srow] = hb;
                Sl[(scol + i) * 72 + srow] = f2bf(vv[i] - bf2f(hb));
            }
        }
        __syncthreads();
#pragma unroll
        for (int s2 = 0; s2 < 2; s2++) {
            bf16x8 aph = *(const bf16x8*)&Ph[(w * 16 + l15) * 72 + s2 * 32 + quad * 8];
            bf16x8 apl = *(const bf16x8*)&Pl[(w * 16 + l15) * 72 + s2 * 32 + quad * 8];
#pragma unroll
            for (int sd = 0; sd < 4; sd++) {
                bf16x8 bvh = *(const bf16x8*)&Sh[(sd * 16 + l15) * 72 + s2 * 32 + quad * 8];
                bf16x8 bvl = *(const bf16x8*)&Sl[(sd * 16 + l15) * 72 + s2 * 32 + quad * 8];
                oacc[sd] = __builtin_amdgcn_mfma_f32_16x16x32_bf16(apl, bvh, oacc[sd], 0, 0, 0);
                oacc[sd] = __builtin_amdgcn_mfma_f32_16x16x32_bf16(aph, bvl, oacc[sd], 0, 0, 0);
                oacc[sd] = __builtin_amdgcn_mfma_f32_16x16x32_bf16(aph, bvh, oacc[sd], 0, 0, 0);
            }
        }
        __syncthreads();
    }

#pragma unroll
    for (int sd = 0; sd < 4; sd++) {
#pragma unroll
        for (int r = 0; r < 4; r++) {
            int q = qbase + w * 16 + quad * 4 + r;
            if (q < SEQ) {
                float val = oacc[sd][r] * inv[r];
                u16 hb = f2bf(val);
                size_t o = ((size_t)(b * SEQ + q)) * 768 + h * 64 + sd * 16 + l15;
                ohi[o] = hb;
                olo[o] = f2bf(val - bf2f(hb));
            }
        }
    }
}

// ---------------- LN2 + gate (top-2 of 8) ----------------
__global__ __launch_bounds__(256) void ln2_gate_kernel(const float* __restrict__ x1,
        const float* __restrict__ g, const float* __restrict__ b, const float* __restrict__ wg,
        u16* __restrict__ flat, int2* __restrict__ idx, float2* __restrict__ gate) {
    int t = blockIdx.x, tid = threadIdx.x;
    int w = tid >> 6, lane = tid & 63;
    float v[3];
#pragma unroll
    for (int i = 0; i < 3; i++) v[i] = x1[(size_t)t * 768 + tid + i * 256];
    float s = v[0] + v[1] + v[2];
    float q = v[0] * v[0] + v[1] * v[1] + v[2] * v[2];
    s = wred_sum(s); q = wred_sum(q);
    __shared__ float red[8];
    __shared__ float fs[768];
    __shared__ float lg[8];
    if (lane == 0) { red[w] = s; red[4 + w] = q; }
    __syncthreads();
    float st = red[0] + red[1] + red[2] + red[3];
    float qt = red[4] + red[5] + red[6] + red[7];
    float mean = st * (1.f / 768.f);
    float var = qt * (1.f / 768.f) - mean * mean;
    float rs = rsqrtf(var + 1e-5f);
#pragma unroll
    for (int i = 0; i < 3; i++) {
        int d = tid + i * 256;
        float f = (v[i] - mean) * rs * g[d] + b[d];
        flat[(size_t)t * 768 + d] = f2bf(f);
        fs[d] = f;
    }
    __syncthreads();
    int e0 = 2 * w, e1 = 2 * w + 1;
    float p0 = 0.f, p1 = 0.f;
    for (int d = lane; d < 768; d += 64) {
        float f = fs[d];
        p0 += f * wg[d * 8 + e0];
        p1 += f * wg[d * 8 + e1];
    }
    p0 = wred_sum(p0); p1 = wred_sum(p1);
    if (lane == 0) { lg[e0] = p0; lg[e1] = p1; }
    __syncthreads();
    if (tid == 0) {
        float b0 = -1e30f, b1 = -1e30f;
        int i0 = 0, i1 = 0;
        for (int e = 0; e < 8; e++) {     // strict > keeps first occurrence (jax tie-break)
            float le = lg[e];
            if (le > b0) { b1 = b0; i1 = i0; b0 = le; i0 = e; }
            else if (le > b1) { b1 = le; i1 = e; }
        }
        float ex = expf(b1 - b0);
        float den = 1.f + ex;
        idx[t] = make_int2(i0, i1);
        gate[t] = make_float2(1.f / den, ex / den);
    }
}

// ---------------- routing ----------------
__global__ __launch_bounds__(256) void hist_kernel(const int2* __restrict__ idx, int* __restrict__ cnt) {
    int t = blockIdx.x * 256 + threadIdx.x;
    if (t < T_TOK) {
        int2 id = idx[t];
        atomicAdd(&cnt[id.x], 1);
        atomicAdd(&cnt[id.y], 1);
    }
}

__global__ void offsets_kernel(const int* __restrict__ cnt, int* __restrict__ asg) {
    if (threadIdx.x == 0 && blockIdx.x == 0) {
        int acc = 0;
        asg[0] = 0;
        for (int e = 0; e < 8; e++) { acc += (cnt[e] + 127) & ~127; asg[e + 1] = acc; }
    }
}

__global__ __launch_bounds__(256) void scatter_kernel(const int2* __restrict__ idx,
        const int* __restrict__ asg, int* __restrict__ cursor,
        int* __restrict__ list, int* __restrict__ pos) {
    int t = blockIdx.x * 256 + threadIdx.x;
    if (t >= T_TOK) return;
    int2 id = idx[t];
    int p0 = asg[id.x] + atomicAdd(&cursor[id.x], 1);
    list[p0] = t * 2;
    pos[t * 2] = p0;
    int p1 = asg[id.y] + atomicAdd(&cursor[id.y], 1);
    list[p1] = t * 2 + 1;
    pos[t * 2 + 1] = p1;
}

// ---------------- final: out = x1 + g0*y[p0] + g1*y[p1]  (f32 out) ----------------
__global__ __launch_bounds__(256) void final_kernel(const float* __restrict__ x1,
        const float* __restrict__ yp, const int* __restrict__ pos,
        const float2* __restrict__ gate, float* __restrict__ out) {
    int t = blockIdx.x, tid = threadIdx.x;
    float2 g = gate[t];
    int p0 = pos[t * 2], p1 = pos[t * 2 + 1];
#pragma unroll
    for (int i = 0; i < 3; i++) {
        int d = tid + i * 256;
        float y = g.x * yp[(size_t)p0 * 768 + d] + g.y * yp[(size_t)p1 * 768 + d];
        out[(size_t)t * 768 + d] = x1[(size_t)t * 768 + d] + y;
    }
}

extern "C" void kernel_launch(void* const* d_in, const int* in_sizes, int n_in,
                              void* d_out, int out_size, void* d_ws, size_t ws_size,
                              hipStream_t stream) {
    const float* x      = (const float*)d_in[0];
    const float* ln1_g  = (const float*)d_in[1];
    const float* ln1_b  = (const float*)d_in[2];
    const float* qkv_w  = (const float*)d_in[3];
    const float* qkv_b  = (const float*)d_in[4];
    const float* proj_w = (const float*)d_in[5];
    const float* proj_b = (const float*)d_in[6];
    const float* ln2_g  = (const float*)d_in[7];
    const float* ln2_b  = (const float*)d_in[8];
    const float* w_gate = (const float*)d_in[9];
    const float* w1     = (const float*)d_in[10];
    const float* b1     = (const float*)d_in[11];
    const float* w2     = (const float*)d_in[12];
    const float* b2     = (const float*)d_in[13];

    char* ws = (char*)d_ws;
    size_t off = 0;
    auto alloc = [&](size_t bytes) { size_t cur = off; off = (off + bytes + 255) & ~(size_t)255; return cur; };
    // region0: h_hi|h_lo|qkvf|o_hi|o_lo (dead before MoE2) — reused as ypair
    u16*    h_hi  = (u16*)   (ws + alloc((size_t)T_TOK * 768 * 2));
    u16*    h_lo  = (u16*)   (ws + alloc((size_t)T_TOK * 768 * 2));
    float*  qkvf  = (float*) (ws + alloc((size_t)T_TOK * 2304 * 4));
    u16*    o_hi  = (u16*)   (ws + alloc((size_t)T_TOK * 768 * 2));
    u16*    o_lo  = (u16*)   (ws + alloc((size_t)T_TOK * 768 * 2));
    float*  ypair = (float*) ws;   // 7424*768*4 = 22.8MB <= region0 ~48MB
    float*  x1    = (float*) (ws + alloc((size_t)T_TOK * 768 * 4));
    u16*    flat  = (u16*)   (ws + alloc((size_t)T_TOK * 768 * 2));
    int2*   idx   = (int2*)  (ws + alloc((size_t)T_TOK * 8));
    float2* gate  = (float2*)(ws + alloc((size_t)T_TOK * 8));
    int*    cnt   = (int*)   (ws + alloc(64));     // cnt[8] + cursor[8]
    int*    cursor = cnt + 8;
    int*    asg   = (int*)   (ws + alloc(64));     // aligned_start[9]
    int*    list  = (int*)   (ws + alloc((size_t)LISTN * 4));
    int*    pos   = (int*)   (ws + alloc((size_t)T_TOK * 2 * 4));
    u16*    hid   = (u16*)   (ws + alloc((size_t)LISTN * 3072 * 2));
    u16*    qkvt_h = (u16*)  (ws + alloc((size_t)2304 * 768 * 2));
    u16*    qkvt_l = (u16*)  (ws + alloc((size_t)2304 * 768 * 2));
    u16*    projt_h = (u16*) (ws + alloc((size_t)768 * 768 * 2));
    u16*    projt_l = (u16*) (ws + alloc((size_t)768 * 768 * 2));
    u16*    w1t   = (u16*)   (ws + alloc((size_t)8 * 3072 * 768 * 2));
    u16*    w2t   = (u16*)   (ws + alloc((size_t)8 * 768 * 3072 * 2));

    hipMemsetAsync(cnt, 0, 64, stream);
    hipMemsetAsync(list, 0xFF, (size_t)LISTN * 4, stream);

    // weight prep (bf16, [n][k] layout; qkv/proj split hi/lo)
    transp_kernel<1><<<dim3(12, 36, 1), 256, 0, stream>>>(qkv_w, qkvt_h, qkvt_l, 768, 2304);
    transp_kernel<1><<<dim3(12, 12, 1), 256, 0, stream>>>(proj_w, projt_h, projt_l, 768, 768);
    transp_kernel<0><<<dim3(12, 48, 8), 256, 0, stream>>>(w1, w1t, nullptr, 768, 3072);
    transp_kernel<0><<<dim3(48, 12, 8), 256, 0, stream>>>(w2, w2t, nullptr, 3072, 768);

    ln1_kernel<<<T_TOK, 256, 0, stream>>>(x, ln1_g, ln1_b, h_hi, h_lo);
    gemm128<0><<<dim3(25, 18), 256, 0, stream>>>(h_hi, h_lo, qkvt_h, qkvt_l, qkv_b, qkvf,
                                                 nullptr, nullptr, nullptr, T_TOK, 2304, 768);
    attn_mfma_kernel<<<dim3(4, 192), 256, 0, stream>>>(qkvf, o_hi, o_lo);
    gemm128<1><<<dim3(25, 6), 256, 0, stream>>>(o_hi, o_lo, projt_h, projt_l, proj_b, x1,
                                                x, nullptr, nullptr, T_TOK, 768, 768);
    ln2_gate_kernel<<<T_TOK, 256, 0, stream>>>(x1, ln2_g, ln2_b, w_gate, flat, idx, gate);
    hist_kernel<<<(T_TOK + 255) / 256, 256, 0, stream>>>(idx, cnt);
    offsets_kernel<<<1, 64, 0, stream>>>(cnt, asg);
    scatter_kernel<<<(T_TOK + 255) / 256, 256, 0, stream>>>(idx, asg, cursor, list, pos);
    gemm128<2><<<dim3(MOE_MT, 24), 256, 0, stream>>>(flat, nullptr, w1t, nullptr, b1, hid,
                                                     nullptr, list, asg, LISTN, 3072, 768);
    gemm128<3><<<dim3(MOE_MT, 6), 256, 0, stream>>>(hid, nullptr, w2t, nullptr, b2, ypair,
                                                    nullptr, list, asg, LISTN, 768, 3072);
    final_kernel<<<T_TOK, 256, 0, stream>>>(x1, ypair, pos, gate, (float*)d_out);
}